// Round 2
// baseline (398.367 us; speedup 1.0000x reference)
//
#include <hip/hip_runtime.h>

#define NPTS 65552          // 16 * (64*64 + 1)
#define MPAD 65664          // 513 * 128
#define NVOX 274625         // 65^3

typedef unsigned short u16;
typedef __attribute__((ext_vector_type(8))) short bf16x8;
typedef __attribute__((ext_vector_type(4))) float f32x4;
typedef __attribute__((ext_vector_type(4))) unsigned short us4;

__device__ __forceinline__ u16 f2bf(float f) {
  unsigned int u = __float_as_uint(f);
  return (u16)((u + 0x7FFFu + ((u >> 16) & 1u)) >> 16);
}

// ---------------- coords from depth ----------------
__global__ void coords_kernel(const float* __restrict__ depth, int* __restrict__ pcoord) {
  int b = blockIdx.x, tid = threadIdx.x;
  const float* d = depth + b * 4096;
  float mn = 1e30f, mx = -1e30f;
  for (int p = tid; p < 4096; p += 256) {
    float v = d[p];
    mn = fminf(mn, v);
    mx = fmaxf(mx, v);
  }
  __shared__ float smn[256], smx[256];
  smn[tid] = mn; smx[tid] = mx;
  __syncthreads();
  for (int s = 128; s > 0; s >>= 1) {
    if (tid < s) {
      smn[tid] = fminf(smn[tid], smn[tid + s]);
      smx[tid] = fmaxf(smx[tid], smx[tid + s]);
    }
    __syncthreads();
  }
  mn = smn[0]; mx = smx[0];
  float den = mx - mn + 1e-8f;
  for (int p = tid; p < 4096; p += 256) {
    int i = p >> 6, j = p & 63;
    float x = (float)j / 63.0f;       // matches jnp arange/63 (IEEE div)
    float y = (float)i / 63.0f;
    float z = (d[p] - mn) / den;
    int cx = (int)rintf(x * 64.0f);   // *64 exact, rintf = round-half-even
    int cy = (int)rintf(y * 64.0f);
    int cz = (int)rintf(z * 64.0f);
    cx = min(max(cx, 0), 64); cy = min(max(cy, 0), 64); cz = min(max(cz, 0), 64);
    pcoord[b * 4097 + 1 + p] = cx | (cy << 8) | (cz << 16);
  }
  if (tid == 0) pcoord[b * 4097] = 0;   // cls token coord (0,0,0)
}

// ---------------- voxel map ----------------
__global__ void init_idx(int* __restrict__ m) {
  int i = blockIdx.x * 256 + threadIdx.x;
  if (i < NVOX) m[i] = -1;
}

__global__ void scatter_idx(const int* __restrict__ pcoord, int* __restrict__ m) {
  int n = blockIdx.x * 256 + threadIdx.x;
  if (n >= NPTS) return;
  int c = pcoord[n];
  int lin = ((c & 255) * 65 + ((c >> 8) & 255)) * 65 + ((c >> 16) & 255);
  atomicMax(&m[lin], n);
}

// ---------------- neighbor ids: nid[k][n], invalid -> NPTS (zero row) ----------------
__global__ void nbr_kernel(const int* __restrict__ pcoord, const int* __restrict__ m,
                           int* __restrict__ nid) {
  int n = blockIdx.x * 256 + threadIdx.x;
  if (n >= MPAD) return;
  if (n >= NPTS) {
    for (int k = 0; k < 27; ++k) nid[k * MPAD + n] = NPTS;
    return;
  }
  int c = pcoord[n];
  int cx = c & 255, cy = (c >> 8) & 255, cz = (c >> 16) & 255;
#pragma unroll
  for (int k = 0; k < 27; ++k) {
    int nx = cx + k / 9 - 1;
    int ny = cy + (k / 3) % 3 - 1;
    int nz = cz + k % 3 - 1;
    int id = NPTS;
    if (((unsigned)nx <= 64u) && ((unsigned)ny <= 64u) && ((unsigned)nz <= 64u)) {
      int v = m[(nx * 65 + ny) * 65 + nz];
      if (v >= 0) id = v;
    }
    nid[k * MPAD + n] = id;
  }
}

// ---------------- features fp32 -> bf16 (+ zero row at NPTS) ----------------
__global__ void conv_feat(const float* __restrict__ f, u16* __restrict__ o) {
  int q = blockIdx.x * 256 + threadIdx.x;       // quad index
  if (q >= (NPTS + 1) * 64) return;
  us4 r;
  if (q < NPTS * 64) {
    float4 v = ((const float4*)f)[q];
    r.x = f2bf(v.x); r.y = f2bf(v.y); r.z = f2bf(v.z); r.w = f2bf(v.w);
  } else {
    r.x = 0; r.y = 0; r.z = 0; r.w = 0;
  }
  ((us4*)o)[q] = r;
}

// -------- weight fp32 [27][ci][co] -> bf16 wt2[ko][ks(8)][lk(4)][co(256)][8]
// Layout matches GEMM LDS staging exactly: per (ko,ks) a contiguous 16KB B-tile
// in [lk][row][16B] order so global_load_lds staging is fully linear.
__global__ void conv_wt2(const float* __restrict__ w, u16* __restrict__ wt2) {
  int u = blockIdx.x * 256 + threadIdx.x;       // < 27*65536
  int e = u & 7, row = (u >> 3) & 255, lk = (u >> 11) & 3, ks = (u >> 13) & 7, ko = u >> 16;
  int ci = ks * 32 + lk * 8 + e;
  wt2[u] = f2bf(w[ko * 65536 + ci * 256 + row]);
}

// ---------------- gather-GEMM: out[N,256] = sum_k gather(feat, nid_k) @ W_k ----------------
__device__ __forceinline__ void gload16(const void* g, unsigned int lds_off) {
  __builtin_amdgcn_global_load_lds(
      (__attribute__((address_space(1))) void*)(size_t)g,
      (__attribute__((address_space(3))) void*)(unsigned int)lds_off,
      16, 0, 0);
}

__global__ __launch_bounds__(512) void gemm_kernel(const u16* __restrict__ feat,
                                                   const u16* __restrict__ wt,
                                                   const int* __restrict__ nid,
                                                   float* __restrict__ out) {
  __shared__ u16 As[2][4096];   // [buf][lk(4)][row(128)][8]   8KB / buf
  __shared__ u16 Bs[2][8192];   // [buf][lk(4)][row(256)][8]  16KB / buf
  int bm = blockIdx.x;
  int tid = threadIdx.x;
  int w = tid >> 6, l = tid & 63;
  int wr = w >> 2, wc = w & 3;     // wave tile (wr*64, wc*64)
  int lm = l & 15, lk = l >> 4;

  unsigned A0 = (unsigned)(size_t)&As[0][0];
  unsigned B0 = (unsigned)(size_t)&Bs[0][0];

  const char* featc = (const char*)feat;
  const char* wtc = (const char*)wt;

  int gr = bm * 128 + ((w & 1) << 6) + l;   // A row this lane stages (1 row/lane)
  int aSlotB = (w >> 1) << 4;               // this wave's k-chunk (lk) byte offset

  f32x4 acc[4][4];
#pragma unroll
  for (int m = 0; m < 4; ++m)
#pragma unroll
    for (int n = 0; n < 4; ++n) acc[m][n] = (f32x4){0.f, 0.f, 0.f, 0.f};

  int nv = nid[gr];                 // ko=0 gather row for this lane
  int nv_next = nv;

  // prologue: stage step (ko=0, ks=0) into buf 0
  {
    unsigned aB = A0 + (w << 10);
    unsigned bB = B0 + (w << 11);
    gload16(featc + ((size_t)nv << 9) + aSlotB, aB);
    const char* bs = wtc + (w << 11) + (l << 4);
    gload16(bs, bB);
    gload16(bs + 1024, bB + 1024);
  }
  __syncthreads();

  int cur = 0;
  for (int ko = 0; ko < 27; ++ko) {
    if (ko < 26) nv_next = nid[(ko + 1) * MPAD + gr];   // per-lane nid prefetch
#pragma unroll
    for (int ks = 0; ks < 8; ++ks) {
      // ---- prefetch next K-step into buf cur^1 (issued BEFORE compute) ----
      bool last = (ko == 26) && (ks == 7);
      if (!last) {
        int nks = (ks + 1) & 7;
        int nko = (ks == 7) ? ko + 1 : ko;
        int snv = (ks == 7) ? nv_next : nv;
        unsigned aB = A0 + ((cur ^ 1) << 13) + (w << 10);
        unsigned bB = B0 + ((cur ^ 1) << 14) + (w << 11);
        gload16(featc + ((size_t)snv << 9) + (nks << 6) + aSlotB, aB);
        const char* bs = wtc + ((size_t)(nko * 8 + nks) << 14) + (w << 11) + (l << 4);
        gload16(bs, bB);
        gload16(bs + 1024, bB + 1024);
      }
      // ---- compute current step from buf cur ----
      const bf16x8* Av = (const bf16x8*)&As[cur][0];
      const bf16x8* Bv = (const bf16x8*)&Bs[cur][0];
      bf16x8 a[4], b[4];
#pragma unroll
      for (int m = 0; m < 4; ++m) a[m] = Av[(lk << 7) + (wr << 6) + (m << 4) + lm];
#pragma unroll
      for (int n = 0; n < 4; ++n) b[n] = Bv[(lk << 8) + (wc << 6) + (n << 4) + lm];
#pragma unroll
      for (int m = 0; m < 4; ++m)
#pragma unroll
        for (int n = 0; n < 4; ++n)
          acc[m][n] = __builtin_amdgcn_mfma_f32_16x16x32_bf16(a[m], b[n], acc[m][n], 0, 0, 0);
      __syncthreads();   // drains this step's prefetch vmcnt; guards buffer swap
      cur ^= 1;
    }
    nv = nv_next;
  }

  // epilogue: D row = (lk*4+i), col = lm within each 16x16 frag
#pragma unroll
  for (int m = 0; m < 4; ++m) {
#pragma unroll
    for (int i = 0; i < 4; ++i) {
      int gr2 = bm * 128 + (wr << 6) + (m << 4) + (lk << 2) + i;
      if (gr2 < NPTS) {
        float* po = out + (size_t)gr2 * 256 + (wc << 6) + lm;
#pragma unroll
        for (int n = 0; n < 4; ++n) po[n << 4] = acc[m][n][i];
      }
    }
  }
}

extern "C" void kernel_launch(void* const* d_in, const int* in_sizes, int n_in,
                              void* d_out, int out_size, void* d_ws, size_t ws_size,
                              hipStream_t stream) {
  const float* features = (const float*)d_in[0];
  const float* depth = (const float*)d_in[1];
  const float* weight = (const float*)d_in[2];
  float* out = (float*)d_out;
  char* ws = (char*)d_ws;

  // ws layout (256B aligned)
  int* idx_map = (int*)(ws + 0);              // 274625 ints
  int* pcoord  = (int*)(ws + 1098752);        // 65552 ints
  int* nid     = (int*)(ws + 1361152);        // 27*65664 ints
  u16* feat_bf = (u16*)(ws + 8452864);        // (65552+1)*256 bf16
  u16* wt_bf   = (u16*)(ws + 42016256);       // 27*65536 bf16 (pre-arranged)
  // total ~45.6 MB

  coords_kernel<<<16, 256, 0, stream>>>(depth, pcoord);
  init_idx<<<(NVOX + 255) / 256, 256, 0, stream>>>(idx_map);
  scatter_idx<<<(NPTS + 255) / 256, 256, 0, stream>>>(pcoord, idx_map);
  nbr_kernel<<<(MPAD + 255) / 256, 256, 0, stream>>>(pcoord, idx_map, nid);
  conv_feat<<<((NPTS + 1) * 64 + 255) / 256, 256, 0, stream>>>(features, feat_bf);
  conv_wt2<<<27 * 65536 / 256, 256, 0, stream>>>(weight, wt_bf);
  gemm_kernel<<<513, 512, 0, stream>>>(feat_bf, wt_bf, nid, out);
}

// Round 3
// 389.925 us; speedup vs baseline: 1.0217x; 1.0217x over previous
//
#include <hip/hip_runtime.h>

#define NPTS 65552          // 16 * (64*64 + 1)
#define MPAD 65664          // 513 * 128
#define NVOX 274625         // 65^3

typedef unsigned short u16;
typedef __attribute__((ext_vector_type(8))) short bf16x8;
typedef __attribute__((ext_vector_type(4))) float f32x4;
typedef __attribute__((ext_vector_type(4))) unsigned short us4;

__device__ __forceinline__ u16 f2bf(float f) {
  unsigned int u = __float_as_uint(f);
  return (u16)((u + 0x7FFFu + ((u >> 16) & 1u)) >> 16);
}

// ---------------- coords from depth ----------------
__global__ void coords_kernel(const float* __restrict__ depth, int* __restrict__ pcoord) {
  int b = blockIdx.x, tid = threadIdx.x;
  const float* d = depth + b * 4096;
  float mn = 1e30f, mx = -1e30f;
  for (int p = tid; p < 4096; p += 256) {
    float v = d[p];
    mn = fminf(mn, v);
    mx = fmaxf(mx, v);
  }
  __shared__ float smn[256], smx[256];
  smn[tid] = mn; smx[tid] = mx;
  __syncthreads();
  for (int s = 128; s > 0; s >>= 1) {
    if (tid < s) {
      smn[tid] = fminf(smn[tid], smn[tid + s]);
      smx[tid] = fmaxf(smx[tid], smx[tid + s]);
    }
    __syncthreads();
  }
  mn = smn[0]; mx = smx[0];
  float den = mx - mn + 1e-8f;
  for (int p = tid; p < 4096; p += 256) {
    int i = p >> 6, j = p & 63;
    float x = (float)j / 63.0f;       // matches jnp arange/63 (IEEE div)
    float y = (float)i / 63.0f;
    float z = (d[p] - mn) / den;
    int cx = (int)rintf(x * 64.0f);   // *64 exact, rintf = round-half-even
    int cy = (int)rintf(y * 64.0f);
    int cz = (int)rintf(z * 64.0f);
    cx = min(max(cx, 0), 64); cy = min(max(cy, 0), 64); cz = min(max(cz, 0), 64);
    pcoord[b * 4097 + 1 + p] = cx | (cy << 8) | (cz << 16);
  }
  if (tid == 0) pcoord[b * 4097] = 0;   // cls token coord (0,0,0)
}

// ---------------- voxel map ----------------
__global__ void init_idx(int* __restrict__ m) {
  int i = blockIdx.x * 256 + threadIdx.x;
  if (i < NVOX) m[i] = -1;
}

__global__ void scatter_idx(const int* __restrict__ pcoord, int* __restrict__ m) {
  int n = blockIdx.x * 256 + threadIdx.x;
  if (n >= NPTS) return;
  int c = pcoord[n];
  int lin = ((c & 255) * 65 + ((c >> 8) & 255)) * 65 + ((c >> 16) & 255);
  atomicMax(&m[lin], n);
}

// ---------------- neighbor ids: nid[k][n], invalid -> NPTS (zero row) ----------------
__global__ void nbr_kernel(const int* __restrict__ pcoord, const int* __restrict__ m,
                           int* __restrict__ nid) {
  int n = blockIdx.x * 256 + threadIdx.x;
  if (n >= MPAD) return;
  if (n >= NPTS) {
    for (int k = 0; k < 27; ++k) nid[k * MPAD + n] = NPTS;
    return;
  }
  int c = pcoord[n];
  int cx = c & 255, cy = (c >> 8) & 255, cz = (c >> 16) & 255;
#pragma unroll
  for (int k = 0; k < 27; ++k) {
    int nx = cx + k / 9 - 1;
    int ny = cy + (k / 3) % 3 - 1;
    int nz = cz + k % 3 - 1;
    int id = NPTS;
    if (((unsigned)nx <= 64u) && ((unsigned)ny <= 64u) && ((unsigned)nz <= 64u)) {
      int v = m[(nx * 65 + ny) * 65 + nz];
      if (v >= 0) id = v;
    }
    nid[k * MPAD + n] = id;
  }
}

// ---------------- features fp32 -> bf16 (+ zero row at NPTS) ----------------
__global__ void conv_feat(const float* __restrict__ f, u16* __restrict__ o) {
  int q = blockIdx.x * 256 + threadIdx.x;       // quad index
  if (q >= (NPTS + 1) * 64) return;
  us4 r;
  if (q < NPTS * 64) {
    float4 v = ((const float4*)f)[q];
    r.x = f2bf(v.x); r.y = f2bf(v.y); r.z = f2bf(v.z); r.w = f2bf(v.w);
  } else {
    r.x = 0; r.y = 0; r.z = 0; r.w = 0;
  }
  ((us4*)o)[q] = r;
}

// -------- weight fp32 [27][ci][co] -> bf16 wt2[ko][ks(8)][lk(4)][co(256)][8]
// Layout matches GEMM B LDS staging exactly (fully linear global_load_lds).
__global__ void conv_wt2(const float* __restrict__ w, u16* __restrict__ wt2) {
  int u = blockIdx.x * 256 + threadIdx.x;       // < 27*65536
  int e = u & 7, row = (u >> 3) & 255, lk = (u >> 11) & 3, ks = (u >> 13) & 7, ko = u >> 16;
  int ci = ks * 32 + lk * 8 + e;
  wt2[u] = f2bf(w[ko * 65536 + ci * 256 + row]);
}

// ---------------- gather-GEMM: out[N,256] = sum_k gather(feat, nid_k) @ W_k ----------------
__device__ __forceinline__ void gload16(const void* g, unsigned int lds_off) {
  __builtin_amdgcn_global_load_lds(
      (__attribute__((address_space(1))) void*)(size_t)g,
      (__attribute__((address_space(3))) void*)(unsigned int)lds_off,
      16, 0, 0);
}

__global__ __launch_bounds__(512) void gemm_kernel(const u16* __restrict__ feat,
                                                   const u16* __restrict__ wt,
                                                   const int* __restrict__ nid,
                                                   float* __restrict__ out) {
  __shared__ u16 As[2][4096];   // [buf][row(128)][slot(4)][8e]   8KB / buf (slot XOR-swizzled)
  __shared__ u16 Bs[2][8192];   // [buf][lk(4)][co(256)][8e]     16KB / buf
  int bm = blockIdx.x;
  int tid = threadIdx.x;
  int w = tid >> 6, l = tid & 63;
  int wr = w >> 2, wc = w & 3;     // wave tile (wr*64, wc*64)
  int lm = l & 15, lk = l >> 4;

  unsigned A0 = (unsigned)(size_t)&As[0][0];
  unsigned B0 = (unsigned)(size_t)&Bs[0][0];

  const char* featc = (const char*)feat;
  const char* wtc = (const char*)wt;

  // ---- A staging mapping: 4 lanes per row (coalesced 64B), XOR chunk swizzle ----
  int row_l = (w << 4) + (l >> 2);              // row this lane helps stage (0..127)
  int gmA = bm * 128 + row_l;                   // global point row
  int cA16 = (((l & 3) ^ ((row_l >> 1) & 3)) << 4);  // swizzled chunk byte off in row

  // ---- A ds_read swizzle: chunk lk lives at slot lk ^ ((row>>1)&3); for rows
  // wr*64 + m*16 + lm, (row>>1)&3 == (lm>>1)&3 (m*16, wr*64 contribute 0 mod 8).
  int aswz = lk ^ ((lm >> 1) & 3);

  f32x4 acc[4][4];
#pragma unroll
  for (int m = 0; m < 4; ++m)
#pragma unroll
    for (int n = 0; n < 4; ++n) acc[m][n] = (f32x4){0.f, 0.f, 0.f, 0.f};

  int nv = nid[gmA];                // ko=0 gather row for this lane
  int nv_next = nv;

  // prologue: stage step (ko=0, ks=0) into buf 0
  {
    gload16(featc + ((size_t)nv << 9) + cA16, A0 + (w << 10));
    const char* bs = wtc + (w << 11) + (l << 4);
    gload16(bs, B0 + (w << 11));
    gload16(bs + 1024, B0 + (w << 11) + 1024);
  }
  __syncthreads();

  int cur = 0;
  for (int ko = 0; ko < 27; ++ko) {
    if (ko < 26) nv_next = nid[(ko + 1) * MPAD + gmA];   // per-lane nid prefetch
#pragma unroll
    for (int ks = 0; ks < 8; ++ks) {
      // ---- prefetch next K-step into buf cur^1 (issued BEFORE compute) ----
      bool last = (ko == 26) && (ks == 7);
      if (!last) {
        int nks = (ks + 1) & 7;
        int nko = (ks == 7) ? ko + 1 : ko;
        int snv = (ks == 7) ? nv_next : nv;
        unsigned aB = A0 + ((cur ^ 1) << 13) + (w << 10);
        unsigned bB = B0 + ((cur ^ 1) << 14) + (w << 11);
        gload16(featc + ((size_t)snv << 9) + (nks << 6) + cA16, aB);
        const char* bs = wtc + ((size_t)(nko * 8 + nks) << 14) + (w << 11) + (l << 4);
        gload16(bs, bB);
        gload16(bs + 1024, bB + 1024);
      }
      // ---- compute current step from buf cur ----
      const bf16x8* Av = (const bf16x8*)&As[cur][0];
      const bf16x8* Bv = (const bf16x8*)&Bs[cur][0];
      bf16x8 a[4], b[4];
#pragma unroll
      for (int m = 0; m < 4; ++m)
        a[m] = Av[(((wr << 6) + (m << 4) + lm) << 2) + aswz];
#pragma unroll
      for (int n = 0; n < 4; ++n) b[n] = Bv[(lk << 8) + (wc << 6) + (n << 4) + lm];
#pragma unroll
      for (int m = 0; m < 4; ++m)
#pragma unroll
        for (int n = 0; n < 4; ++n)
          acc[m][n] = __builtin_amdgcn_mfma_f32_16x16x32_bf16(a[m], b[n], acc[m][n], 0, 0, 0);
      __syncthreads();   // drains this step's prefetch vmcnt; guards buffer swap
      cur ^= 1;
    }
    nv = nv_next;
  }

  // epilogue: D row = (lk*4+i), col = lm within each 16x16 frag
#pragma unroll
  for (int m = 0; m < 4; ++m) {
#pragma unroll
    for (int i = 0; i < 4; ++i) {
      int gr2 = bm * 128 + (wr << 6) + (m << 4) + (lk << 2) + i;
      if (gr2 < NPTS) {
        float* po = out + (size_t)gr2 * 256 + (wc << 6) + lm;
#pragma unroll
        for (int n = 0; n < 4; ++n) po[n << 4] = acc[m][n][i];
      }
    }
  }
}

extern "C" void kernel_launch(void* const* d_in, const int* in_sizes, int n_in,
                              void* d_out, int out_size, void* d_ws, size_t ws_size,
                              hipStream_t stream) {
  const float* features = (const float*)d_in[0];
  const float* depth = (const float*)d_in[1];
  const float* weight = (const float*)d_in[2];
  float* out = (float*)d_out;
  char* ws = (char*)d_ws;

  // ws layout (256B aligned)
  int* idx_map = (int*)(ws + 0);              // 274625 ints
  int* pcoord  = (int*)(ws + 1098752);        // 65552 ints
  int* nid     = (int*)(ws + 1361152);        // 27*65664 ints
  u16* feat_bf = (u16*)(ws + 8452864);        // (65552+1)*256 bf16
  u16* wt_bf   = (u16*)(ws + 42016256);       // 27*65536 bf16 (pre-arranged)
  // total ~45.6 MB

  coords_kernel<<<16, 256, 0, stream>>>(depth, pcoord);
  init_idx<<<(NVOX + 255) / 256, 256, 0, stream>>>(idx_map);
  scatter_idx<<<(NPTS + 255) / 256, 256, 0, stream>>>(pcoord, idx_map);
  nbr_kernel<<<(MPAD + 255) / 256, 256, 0, stream>>>(pcoord, idx_map, nid);
  conv_feat<<<((NPTS + 1) * 64 + 255) / 256, 256, 0, stream>>>(features, feat_bf);
  conv_wt2<<<27 * 65536 / 256, 256, 0, stream>>>(weight, wt_bf);
  gemm_kernel<<<513, 512, 0, stream>>>(feat_bf, wt_bf, nid, out);
}

// Round 4
// 260.032 us; speedup vs baseline: 1.5320x; 1.4995x over previous
//
#include <hip/hip_runtime.h>

#define NPTS 65552          // 16 * (64*64 + 1)
#define MPAD 65664          // 513 * 128
#define NVOX 274625         // 65^3

typedef unsigned short u16;
typedef __attribute__((ext_vector_type(8))) short bf16x8;
typedef __attribute__((ext_vector_type(4))) float f32x4;
typedef __attribute__((ext_vector_type(4))) unsigned short us4;

__device__ __forceinline__ u16 f2bf(float f) {
  unsigned int u = __float_as_uint(f);
  return (u16)((u + 0x7FFFu + ((u >> 16) & 1u)) >> 16);
}

// ---------------- coords from depth ----------------
__global__ void coords_kernel(const float* __restrict__ depth, int* __restrict__ pcoord) {
  int b = blockIdx.x, tid = threadIdx.x;
  const float* d = depth + b * 4096;
  float mn = 1e30f, mx = -1e30f;
  for (int p = tid; p < 4096; p += 256) {
    float v = d[p];
    mn = fminf(mn, v);
    mx = fmaxf(mx, v);
  }
  __shared__ float smn[256], smx[256];
  smn[tid] = mn; smx[tid] = mx;
  __syncthreads();
  for (int s = 128; s > 0; s >>= 1) {
    if (tid < s) {
      smn[tid] = fminf(smn[tid], smn[tid + s]);
      smx[tid] = fmaxf(smx[tid], smx[tid + s]);
    }
    __syncthreads();
  }
  mn = smn[0]; mx = smx[0];
  float den = mx - mn + 1e-8f;
  for (int p = tid; p < 4096; p += 256) {
    int i = p >> 6, j = p & 63;
    float x = (float)j / 63.0f;       // matches jnp arange/63 (IEEE div)
    float y = (float)i / 63.0f;
    float z = (d[p] - mn) / den;
    int cx = (int)rintf(x * 64.0f);   // *64 exact, rintf = round-half-even
    int cy = (int)rintf(y * 64.0f);
    int cz = (int)rintf(z * 64.0f);
    cx = min(max(cx, 0), 64); cy = min(max(cy, 0), 64); cz = min(max(cz, 0), 64);
    pcoord[b * 4097 + 1 + p] = cx | (cy << 8) | (cz << 16);
  }
  if (tid == 0) pcoord[b * 4097] = 0;   // cls token coord (0,0,0)
}

// ---------------- voxel map ----------------
__global__ void init_idx(int* __restrict__ m) {
  int i = blockIdx.x * 256 + threadIdx.x;
  if (i < NVOX) m[i] = -1;
}

__global__ void scatter_idx(const int* __restrict__ pcoord, int* __restrict__ m) {
  int n = blockIdx.x * 256 + threadIdx.x;
  if (n >= NPTS) return;
  int c = pcoord[n];
  int lin = ((c & 255) * 65 + ((c >> 8) & 255)) * 65 + ((c >> 16) & 255);
  atomicMax(&m[lin], n);
}

// ---------------- neighbor ids: nid[k][n], invalid -> NPTS (zero row) ----------------
__global__ void nbr_kernel(const int* __restrict__ pcoord, const int* __restrict__ m,
                           int* __restrict__ nid) {
  int n = blockIdx.x * 256 + threadIdx.x;
  if (n >= MPAD) return;
  if (n >= NPTS) {
    for (int k = 0; k < 27; ++k) nid[k * MPAD + n] = NPTS;
    return;
  }
  int c = pcoord[n];
  int cx = c & 255, cy = (c >> 8) & 255, cz = (c >> 16) & 255;
#pragma unroll
  for (int k = 0; k < 27; ++k) {
    int nx = cx + k / 9 - 1;
    int ny = cy + (k / 3) % 3 - 1;
    int nz = cz + k % 3 - 1;
    int id = NPTS;
    if (((unsigned)nx <= 64u) && ((unsigned)ny <= 64u) && ((unsigned)nz <= 64u)) {
      int v = m[(nx * 65 + ny) * 65 + nz];
      if (v >= 0) id = v;
    }
    nid[k * MPAD + n] = id;
  }
}

// ---------------- features fp32 -> bf16 (+ zero row at NPTS) ----------------
__global__ void conv_feat(const float* __restrict__ f, u16* __restrict__ o) {
  int q = blockIdx.x * 256 + threadIdx.x;       // quad index
  if (q >= (NPTS + 1) * 64) return;
  us4 r;
  if (q < NPTS * 64) {
    float4 v = ((const float4*)f)[q];
    r.x = f2bf(v.x); r.y = f2bf(v.y); r.z = f2bf(v.z); r.w = f2bf(v.w);
  } else {
    r.x = 0; r.y = 0; r.z = 0; r.w = 0;
  }
  ((us4*)o)[q] = r;
}

// -------- weight fp32 [27][ci][co] -> bf16 wt2[step(216)][lk(4)][co(256)][8]
// step = ko*8+ks; per step a contiguous 16KB B-tile matching LDS staging.
__global__ void conv_wt2(const float* __restrict__ w, u16* __restrict__ wt2) {
  int u = blockIdx.x * 256 + threadIdx.x;       // < 27*65536
  int e = u & 7, row = (u >> 3) & 255, lk = (u >> 11) & 3, ks = (u >> 13) & 7, ko = u >> 16;
  int ci = ks * 32 + lk * 8 + e;
  wt2[u] = f2bf(w[ko * 65536 + ci * 256 + row]);
}

// ---------------- gather-GEMM: out[N,256] = sum_k gather(feat, nid_k) @ W_k ----------------
__device__ __forceinline__ void gload16(const void* g, unsigned int lds_off) {
  __builtin_amdgcn_global_load_lds(
      (__attribute__((address_space(1))) void*)(size_t)g,
      (__attribute__((address_space(3))) void*)(unsigned int)lds_off,
      16, 0, 0);
}

__global__ __launch_bounds__(512) void gemm_kernel(const u16* __restrict__ feat,
                                                   const u16* __restrict__ wt,
                                                   const int* __restrict__ nid,
                                                   float* __restrict__ out) {
  // 3-deep pipeline buffers
  __shared__ u16 As[3 * 4096];   // per buf: [row(128)][slot(4)][8e]  8KB (slot XOR-swizzled)
  __shared__ u16 Bs[3 * 8192];   // per buf: [lk(4)][co(256)][8e]    16KB
  int bm = blockIdx.x;
  int tid = threadIdx.x;
  int w = tid >> 6, l = tid & 63;
  int wr = w >> 2, wc = w & 3;     // wave tile (wr*64, wc*64)
  int lm = l & 15, lk = l >> 4;

  unsigned A0 = (unsigned)(size_t)&As[0];
  unsigned B0 = (unsigned)(size_t)&Bs[0];
  const char* Asc = (const char*)&As[0];
  const char* Bsc = (const char*)&Bs[0];

  const char* featc = (const char*)feat;
  const char* wtc = (const char*)wt;

  // A staging: 4 lanes per row (coalesced 64B), XOR chunk swizzle on source
  int row_l = (w << 4) + (l >> 2);
  int gmA = bm * 128 + row_l;
  int cA16 = (((l & 3) ^ ((row_l >> 1) & 3)) << 4);
  // A ds_read swizzle (chunk lk at slot lk ^ ((row>>1)&3); row dep reduces to lm)
  int aswz = lk ^ ((lm >> 1) & 3);

  f32x4 acc[4][4];
#pragma unroll
  for (int m = 0; m < 4; ++m)
#pragma unroll
    for (int n = 0; n < 4; ++n) acc[m][n] = (f32x4){0.f, 0.f, 0.f, 0.f};

  int nv = nid[gmA];                // ko=0 gather row
  int nv_next = nv;

  // prologue: stage steps 0,1 into bufs 0,1 (both ko=0)
  {
    gload16(featc + ((size_t)nv << 9) + cA16, A0 + (w << 10));
    const char* bs0 = wtc + (w << 11) + (l << 4);
    gload16(bs0, B0 + (w << 11));
    gload16(bs0 + 1024, B0 + (w << 11) + 1024);
    gload16(featc + ((size_t)nv << 9) + 64 + cA16, A0 + 8192 + (w << 10));
    const char* bs1 = wtc + 16384 + (w << 11) + (l << 4);
    gload16(bs1, B0 + 16384 + (w << 11));
    gload16(bs1 + 1024, B0 + 16384 + (w << 11) + 1024);
  }

  unsigned a0 = 0, a1 = 8192, a2 = 16384;       // A buf byte offsets
  unsigned b0 = 0, b1 = 16384, b2 = 32768;      // B buf byte offsets

  for (int ko = 0; ko < 27; ++ko) {
#pragma unroll
    for (int ks = 0; ks < 8; ++ks) {
      // ---- counted wait: retire exactly this step's 3 staging loads ----
      if (ko == 26 && ks == 7) {
        asm volatile("s_waitcnt vmcnt(0)" ::: "memory");
      } else if (ks == 1) {
        asm volatile("s_waitcnt vmcnt(4)" ::: "memory");   // +1 for boundary nid load
      } else {
        asm volatile("s_waitcnt vmcnt(3)" ::: "memory");
      }
      __builtin_amdgcn_s_barrier();

      // ---- per-ko nid prefetch (issued first at boundary) ----
      if (ks == 0 && ko < 26) nv_next = nid[(ko + 1) * MPAD + gmA];

      // ---- stage step t+2 into bufs (a2,b2); loads stay in flight 2 steps ----
      if (!(ko == 26 && ks >= 6)) {
        int snv = (ks >= 6) ? nv_next : nv;     // step t+2 crosses into ko+1 iff ks>=6
        gload16(featc + ((size_t)snv << 9) + (((ks + 2) & 7) << 6) + cA16,
                A0 + a2 + (w << 10));
        const char* bs = wtc + ((size_t)(ko * 8 + ks + 2) << 14) + (w << 11) + (l << 4);
        gload16(bs, B0 + b2 + (w << 11));
        gload16(bs + 1024, B0 + b2 + (w << 11) + 1024);
      }

      // ---- compute step t from bufs (a0,b0) ----
      const bf16x8* Av = (const bf16x8*)(Asc + a0);
      const bf16x8* Bv = (const bf16x8*)(Bsc + b0);
      bf16x8 a[4], b[4];
#pragma unroll
      for (int m = 0; m < 4; ++m)
        a[m] = Av[(((wr << 6) + (m << 4) + lm) << 2) + aswz];
#pragma unroll
      for (int n = 0; n < 4; ++n) b[n] = Bv[(lk << 8) + (wc << 6) + (n << 4) + lm];
      __builtin_amdgcn_s_setprio(1);
#pragma unroll
      for (int m = 0; m < 4; ++m)
#pragma unroll
        for (int n = 0; n < 4; ++n)
          acc[m][n] = __builtin_amdgcn_mfma_f32_16x16x32_bf16(a[m], b[n], acc[m][n], 0, 0, 0);
      __builtin_amdgcn_s_setprio(0);

      // ---- rotate buffers ----
      unsigned ta = a0; a0 = a1; a1 = a2; a2 = ta;
      unsigned tb = b0; b0 = b1; b1 = b2; b2 = tb;
    }
    nv = nv_next;
  }

  // epilogue: D row = (lk*4+i), col = lm within each 16x16 frag
#pragma unroll
  for (int m = 0; m < 4; ++m) {
#pragma unroll
    for (int i = 0; i < 4; ++i) {
      int gr2 = bm * 128 + (wr << 6) + (m << 4) + (lk << 2) + i;
      if (gr2 < NPTS) {
        float* po = out + (size_t)gr2 * 256 + (wc << 6) + lm;
#pragma unroll
        for (int n = 0; n < 4; ++n) po[n << 4] = acc[m][n][i];
      }
    }
  }
}

extern "C" void kernel_launch(void* const* d_in, const int* in_sizes, int n_in,
                              void* d_out, int out_size, void* d_ws, size_t ws_size,
                              hipStream_t stream) {
  const float* features = (const float*)d_in[0];
  const float* depth = (const float*)d_in[1];
  const float* weight = (const float*)d_in[2];
  float* out = (float*)d_out;
  char* ws = (char*)d_ws;

  // ws layout (256B aligned)
  int* idx_map = (int*)(ws + 0);              // 274625 ints
  int* pcoord  = (int*)(ws + 1098752);        // 65552 ints
  int* nid     = (int*)(ws + 1361152);        // 27*65664 ints
  u16* feat_bf = (u16*)(ws + 8452864);        // (65552+1)*256 bf16
  u16* wt_bf   = (u16*)(ws + 42016256);       // 27*65536 bf16 (pre-arranged)
  // total ~45.6 MB

  coords_kernel<<<16, 256, 0, stream>>>(depth, pcoord);
  init_idx<<<(NVOX + 255) / 256, 256, 0, stream>>>(idx_map);
  scatter_idx<<<(NPTS + 255) / 256, 256, 0, stream>>>(pcoord, idx_map);
  nbr_kernel<<<(MPAD + 255) / 256, 256, 0, stream>>>(pcoord, idx_map, nid);
  conv_feat<<<((NPTS + 1) * 64 + 255) / 256, 256, 0, stream>>>(features, feat_bf);
  conv_wt2<<<27 * 65536 / 256, 256, 0, stream>>>(weight, wt_bf);
  gemm_kernel<<<513, 512, 0, stream>>>(feat_bf, wt_bf, nid, out);
}